// Round 18
// baseline (616.730 us; speedup 1.0000x reference)
//
#include <hip/hip_runtime.h>
#include <hip/hip_bf16.h>
#include <math.h>
#include <stdint.h>

#define T_SEQ 1024
#define D_DIM 256
#define NH_C 4
#define N_DIM 8192
#define VOCAB_C 256
#define NLAYER 3
#define TWO_PI_F 6.283185307179586f
#define KSPLIT_DEC 32
#define KSPLIT_SC 3

typedef __bf16 bf16x8 __attribute__((ext_vector_type(8)));
typedef float f32x4 __attribute__((ext_vector_type(4)));

__device__ __forceinline__ unsigned short f2bf(float f) {
  unsigned u = __builtin_bit_cast(unsigned, f);
  u += 0x7fffu + ((u >> 16) & 1u);
  return (unsigned short)(u >> 16);
}
__device__ __forceinline__ float bf2f(unsigned short h) {
  unsigned u = ((unsigned)h) << 16;
  return __builtin_bit_cast(float, u);
}
__device__ __forceinline__ unsigned pack2(float a, float b) {
  return (unsigned)f2bf(a) | ((unsigned)f2bf(b) << 16);
}

// direct global->LDS 16B async copy. LDS dest = wave-uniform base + lane*16
// (linear); bank swizzle on the GLOBAL source col, mirrored on ds_read (rule #21).
typedef __attribute__((address_space(3))) uint32_t lds_u32;
typedef __attribute__((address_space(1))) const uint32_t glob_u32;
__device__ __forceinline__ void gload_lds16(const void* g, void* l) {
  __builtin_amdgcn_global_load_lds(reinterpret_cast<glob_u32*>(reinterpret_cast<uintptr_t>(g)),
                                   reinterpret_cast<lds_u32*>(reinterpret_cast<uintptr_t>(l)), 16, 0,
                                   0);
}

// ---------------- transpose f32 [R][C] -> bf16 [C][R], batched over z ----------
__global__ void k_transpose(const float* __restrict__ src, unsigned short* __restrict__ dst,
                            int R, int C, long sB, long dB) {
  __shared__ float tile[32][33];
  const int b = blockIdx.z;
  src += (size_t)b * sB;
  dst += (size_t)b * dB;
  const int c0 = blockIdx.x * 32, r0 = blockIdx.y * 32;
  const int tx = threadIdx.x, ty = threadIdx.y;  // 32 x 8
#pragma unroll
  for (int i = 0; i < 32; i += 8)
    tile[ty + i][tx] = src[(size_t)(r0 + ty + i) * C + (c0 + tx)];
  __syncthreads();
#pragma unroll
  for (int i = 0; i < 32; i += 8)
    dst[(size_t)(c0 + ty + i) * R + (r0 + tx)] = f2bf(tile[tx][ty + i]);
}

// ------- rope cos/sin table, TRANSPOSED + bf16-packed: cs[pair][t] = c|s<<16 ----
__global__ void k_ropetab(unsigned* __restrict__ cs) {
  const int id = blockIdx.x * 256 + threadIdx.x;  // pair*1024 + t
  const int pair = id >> 10, t = id & 1023;
  const float freq = exp2f(-(float)pair * (1.0f / 256.0f)) * (1.0f / TWO_PI_F);
  float ph = (float)t * freq;
  ph -= floorf(ph);
  float s, c;
  __sincosf(ph * TWO_PI_F, &s, &c);
  cs[id] = pack2(c, s);
}

// ---------------- one-wave LayerNorm stats over 256 elems ----------------------
__device__ __forceinline__ void stats256(float4 v, float& mu, float& rs) {
  float s = v.x + v.y + v.z + v.w;
  float ss = v.x * v.x + v.y * v.y + v.z * v.z + v.w * v.w;
#pragma unroll
  for (int o = 1; o < 64; o <<= 1) { s += __shfl_xor(s, o); ss += __shfl_xor(ss, o); }
  mu = s * (1.0f / 256.0f);
  float var = ss * (1.0f / 256.0f) - mu * mu;
  rs = rsqrtf(var + 1e-5f);
}

__global__ void k_embed_ln(const int* __restrict__ idx, const float* __restrict__ embed,
                           float* __restrict__ x, unsigned short* __restrict__ xb,
                           unsigned short* __restrict__ xT) {
  const int t = blockIdx.x, lane = threadIdx.x;  // 64 threads
  const float* row = embed + (size_t)idx[t] * D_DIM;
  float4 v = ((const float4*)row)[lane];
  float mu, rs;
  stats256(v, mu, rs);
  float4 o = make_float4((v.x - mu) * rs, (v.y - mu) * rs, (v.z - mu) * rs, (v.w - mu) * rs);
  ((float4*)(x + (size_t)t * D_DIM))[lane] = o;
  ((uint2*)(xb + (size_t)t * D_DIM))[lane] = make_uint2(pack2(o.x, o.y), pack2(o.z, o.w));
  const int d0 = lane * 4;
  xT[(size_t)(d0 + 0) * T_SEQ + t] = f2bf(o.x);
  xT[(size_t)(d0 + 1) * T_SEQ + t] = f2bf(o.y);
  xT[(size_t)(d0 + 2) * T_SEQ + t] = f2bf(o.z);
  xT[(size_t)(d0 + 3) * T_SEQ + t] = f2bf(o.w);
}

__global__ void k_ln_rows(const float* __restrict__ in, unsigned short* __restrict__ outb) {
  const int r = blockIdx.x, lane = threadIdx.x;
  float4 v = ((const float4*)(in + (size_t)r * D_DIM))[lane];
  float mu, rs;
  stats256(v, mu, rs);
  ((uint2*)(outb + (size_t)r * D_DIM))[lane] =
      make_uint2(pack2((v.x - mu) * rs, (v.y - mu) * rs), pack2((v.z - mu) * rs, (v.w - mu) * rs));
}

// x = LN(x + LN(sum_p ymlp[p]))
template <int NP>
__global__ void k_update_x(const float* __restrict__ ymlp, float* __restrict__ x,
                           unsigned short* __restrict__ xb, unsigned short* __restrict__ xT) {
  const int t = blockIdx.x, lane = threadIdx.x;
  float4 m = make_float4(0.f, 0.f, 0.f, 0.f);
#pragma unroll
  for (int pp = 0; pp < NP; ++pp) {
    float4 q = ((const float4*)(ymlp + (size_t)pp * T_SEQ * D_DIM + (size_t)t * D_DIM))[lane];
    m.x += q.x; m.y += q.y; m.z += q.z; m.w += q.w;
  }
  float mu1, rs1;
  stats256(m, mu1, rs1);
  float4 xv = ((const float4*)(x + (size_t)t * D_DIM))[lane];
  float4 z = make_float4(xv.x + (m.x - mu1) * rs1, xv.y + (m.y - mu1) * rs1,
                         xv.z + (m.z - mu1) * rs1, xv.w + (m.w - mu1) * rs1);
  float mu2, rs2;
  stats256(z, mu2, rs2);
  float4 o = make_float4((z.x - mu2) * rs2, (z.y - mu2) * rs2, (z.z - mu2) * rs2, (z.w - mu2) * rs2);
  ((float4*)(x + (size_t)t * D_DIM))[lane] = o;
  ((uint2*)(xb + (size_t)t * D_DIM))[lane] = make_uint2(pack2(o.x, o.y), pack2(o.z, o.w));
  const int d0 = lane * 4;
  xT[(size_t)(d0 + 0) * T_SEQ + t] = f2bf(o.x);
  xT[(size_t)(d0 + 1) * T_SEQ + t] = f2bf(o.y);
  xT[(size_t)(d0 + 2) * T_SEQ + t] = f2bf(o.z);
  xT[(size_t)(d0 + 3) * T_SEQ + t] = f2bf(o.w);
}

// combine NP TILE-PACKED split-K score partials + strict-lower mask -> bf16.
// Partials layout: [(h*NP+pp)][tile36][128][128] f32, tile = by*(by+1)/2+bx over
// 128x128 lower-tri tiles. Upper-tri of sc keeps its one-time memset zeros.
template <int NP>
__global__ void k_comb(const float* __restrict__ sp, unsigned short* __restrict__ sc) {
  const size_t gid = (size_t)blockIdx.x * 256 + threadIdx.x;  // per 8 elems
  const size_t e0 = gid * 8;
  const int s = (int)(e0 & (T_SEQ - 1));
  const int t = (int)((e0 >> 10) & (T_SEQ - 1));
  if (s >= t) return;  // entire 8-run masked (strict lower: need s < t)
  const int h = (int)(e0 >> 20);
  const int by = t >> 7, bx = s >> 7;                       // 128-tile coords
  const size_t tin = (size_t)(by * (by + 1) / 2 + bx);      // lower-tri tile idx
  const size_t off = (size_t)(t & 127) * 128 + (s & 127);   // in-tile offset
  float v[8] = {0.f, 0.f, 0.f, 0.f, 0.f, 0.f, 0.f, 0.f};
#pragma unroll
  for (int pp = 0; pp < NP; ++pp) {
    const float* a = sp + (((size_t)(h * NP + pp) * 36 + tin) << 14) + off;
    float4 a0 = *(const float4*)a, a1 = *(const float4*)(a + 4);
    v[0] += a0.x; v[1] += a0.y; v[2] += a0.z; v[3] += a0.w;
    v[4] += a1.x; v[5] += a1.y; v[6] += a1.z; v[7] += a1.w;
  }
  unsigned short o[8];
#pragma unroll
  for (int j = 0; j < 8; ++j) o[j] = (s + j < t) ? f2bf(v[j]) : (unsigned short)0;
  *(uint4*)(sc + e0) = *(uint4*)o;
}

// ---------------- pipelined NT bf16 MFMA GEMM: C[i][j] = sum_k A[i][k]*B[j][k] --
// 2-phase double-buffer, global_load_lds staging, both-sides XOR bank swizzle,
// bijective XCD-chunked block swizzle.
// MODE 0: f32 store | 2: scores exact lower-tri grid, strict-lower mask -> bf16
// MODE 3: xy = relu(acc) * inverse-rope-gate(qr) -> separate xy buffer.
//         Gate tile (32 KB) is PREFETCHED into the free LDS buffer during the
//         last K-tile's compute; epilogue gate reads are LDS-local.
// MODE 4: qr = rope(relu(acc)) only. ctab slice (32 KB) prefetched into free
//         LDS buffer during last K-tile; epilogue cos/sin reads are LDS-local.
// MODE 6: scores supertile tri grid + split-K=3 (uneven 42/43/43 nt),
//         TILE-PACKED f32 partials (local 128x128 write at tile base)
// MODE 7: split-K f32 partials (decoder; A = xy [h][T][N] head-flat K)
template <int MODE, int BM, int BN, bool TRI_A, bool SWAPXY>
__global__ __launch_bounds__(256) void k_gemm(const unsigned short* __restrict__ A, long lda, long sAz,
                                              const unsigned short* __restrict__ B, long ldb, long sBz,
                                              void* __restrict__ Cv, long ldc, long sCz,
                                              const unsigned short* __restrict__ extra, long sEz,
                                              unsigned short* __restrict__ C2,
                                              const unsigned* __restrict__ ctab, int Ksize) {
  constexpr int MF = BM / 32;
  constexpr int NF = BN / 32;
  constexpr int BUFB = (BM + BN) * 128;  // bytes per LDS buffer (BK=64)

  // T1: bijective XCD-chunked swizzle (m204) over the full linear grid
  const unsigned nbx = gridDim.x, nby = gridDim.y;
  const unsigned total = nbx * nby * gridDim.z;
  const unsigned lid = (blockIdx.z * nby + blockIdx.y) * nbx + blockIdx.x;
  const unsigned qq = total >> 3, rr = total & 7;
  const unsigned xcd = lid & 7, loc = lid >> 3;
  const unsigned wg = (xcd < rr ? xcd * (qq + 1) : rr * (qq + 1) + (xcd - rr) * qq) + loc;

  int bx, by, bz, zAB, kbase = 0, nt6 = 0, tIdx = 0;
  if constexpr (MODE == 2 || MODE == 6) {
    constexpr int NRT = T_SEQ / BM;
    constexpr int TPH = NRT * (NRT + 1) / 2;
    const int zz = wg / TPH;
    const int tt = wg % TPH;
    if constexpr (MODE == 6 && NRT == 8) {
      // 2x2 supertile traversal of the 8x8 lower triangle
      int srow, rem;
      if (tt < 3)       { srow = 0; rem = tt; }
      else if (tt < 10) { srow = 1; rem = tt - 3; }
      else if (tt < 21) { srow = 2; rem = tt - 10; }
      else              { srow = 3; rem = tt - 21; }
      int scol, lr, lc;
      if (rem < 4 * srow) {
        scol = rem >> 2;
        lr = rem & 1;
        lc = (rem >> 1) & 1;
      } else {
        const int l = rem - 4 * srow;
        scol = srow;
        lr = (l >= 1);
        lc = (l == 2);
      }
      by = srow * 2 + lr;
      bx = scol * 2 + lc;
    } else {
      by = (int)((sqrtf(8.0f * (float)tt + 1.0f) - 1.0f) * 0.5f);
      if (by > NRT - 1) by = NRT - 1;
      while ((by + 1) * (by + 2) / 2 <= tt) ++by;
      while (by * (by + 1) / 2 > tt) --by;
      bx = tt - by * (by + 1) / 2;  // bx <= by
    }
    bz = zz;
    if constexpr (MODE == 6) {
      // split-K=3, uneven 64-unit slices: s0 = (slice*ub)/3 -> 42/43/43
      const int ub = Ksize / 64;
      const int slice = zz % KSPLIT_SC;
      zAB = zz / KSPLIT_SC;  // head
      const int s0 = (slice * ub) / KSPLIT_SC;
      const int s1 = ((slice + 1) * ub) / KSPLIT_SC;
      kbase = s0 * 64;
      nt6 = s1 - s0;
      tIdx = by * (by + 1) / 2 + bx;  // packed lower-tri tile index
    } else {
      zAB = zz;
    }
  } else if constexpr (SWAPXY) {
    by = wg % nby;
    bx = (wg / nby) % nbx;
    bz = wg / (nbx * nby);
    zAB = bz;
  } else {
    bx = wg % nbx;
    by = (wg / nbx) % nby;
    bz = wg / (nbx * nby);
    zAB = bz;
  }
  if constexpr (MODE == 7) kbase = bz * Ksize;

  const int i0 = by * BM;
  const int j0 = bx * BN;

  A += (size_t)zAB * sAz;
  B += (size_t)zAB * sBz;
  float* Cf;
  if constexpr (MODE == 6) {
    Cf = (float*)Cv + (((size_t)bz * 36 + tIdx) << 14);  // tile base (128x128 f32)
  } else {
    Cf = (float*)Cv + (size_t)bz * sCz;
  }
  unsigned short* Ch = (unsigned short*)Cv + (size_t)bz * sCz;
  const unsigned short* E = extra ? extra + (size_t)bz * sEz : nullptr;

  const int tid = threadIdx.x;
  const int lane = tid & 63, w = tid >> 6;
  const int wr = w >> 1, wc = w & 1;  // 2x2 wave grid

  __shared__ __align__(16) char lds[2 * BUFB];

  f32x4 acc[MF][NF];
#pragma unroll
  for (int m = 0; m < MF; ++m)
#pragma unroll
    for (int n = 0; n < NF; ++n) acc[m][n] = f32x4{0.f, 0.f, 0.f, 0.f};

  const char* Abytes = (const char*)A;
  const char* Bbytes = (const char*)B;
  const size_t ldab = (size_t)((MODE == 7) ? N_DIM : lda) * 2;
  const size_t ldbb = (size_t)ldb * 2;
  const int lr2 = lane >> 3;                        // 8 rows x 128B per wave-issue
  const int scol2 = ((lane & 7) * 16) ^ (lr2 << 4); // pre-swizzled source col

  auto stage = [&](int buf, int kt) {
    const int kk = kbase + kt * 64;
    const char* Ag;
    if constexpr (MODE == 7) {  // A = xy [h][T][N], flat k = h*N + n
      Ag = Abytes +
           ((size_t)(kk >> 13) * ((size_t)T_SEQ * N_DIM) + (size_t)i0 * N_DIM + (kk & (N_DIM - 1))) * 2;
    } else {
      Ag = Abytes + ((size_t)i0 * lda + kk) * 2;
    }
    const char* Bg = Bbytes + ((size_t)j0 * ldb + kk) * 2;
    char* lb = lds + buf * BUFB;
#pragma unroll
    for (int it = 0; it < BM / 32; ++it) {
      const int r0 = (w + 4 * it) * 8;
      gload_lds16(Ag + (size_t)(r0 + lr2) * ldab + scol2, lb + r0 * 128);
    }
#pragma unroll
    for (int it = 0; it < BN / 32; ++it) {
      const int r0 = (w + 4 * it) * 8;
      gload_lds16(Bg + (size_t)(r0 + lr2) * ldbb + scol2, lb + BM * 128 + r0 * 128);
    }
  };

  // epilogue-operand prefetch into the free LDS buffer (last K-tile only)
  auto stage_epi = [&](int buf) {
    char* lb = lds + buf * BUFB;
    if constexpr (MODE == 3) {
      // gate tile E[i0..i0+128)[j0..j0+128) bf16, linear [128][256B] = 32 KB
      const char* Eb = (const char*)E;
#pragma unroll
      for (int it = 0; it < 8; ++it) {
        const int ob = it * 4096 + tid * 16;
        const int row = ob >> 8;   // 256B rows
        const int inb = ob & 255;
        gload_lds16(Eb + (size_t)(i0 + row) * ((size_t)ldc * 2) + (size_t)j0 * 2 + inb, lb + ob);
      }
    } else if constexpr (MODE == 4) {
      // ctab slice [pair j0/2 .. +64)[t i0 .. +128) u32, linear [64][512B] = 32 KB
      const char* Cb = (const char*)ctab;
#pragma unroll
      for (int it = 0; it < 8; ++it) {
        const int ob = it * 4096 + tid * 16;
        const int prow = ob >> 9;  // 512B pair-rows
        const int inb = ob & 511;
        gload_lds16(Cb + (size_t)((j0 >> 1) + prow) * (T_SEQ * 4) + (size_t)i0 * 4 + inb, lb + ob);
      }
    }
  };

  const int ar = lane & 15;
  const int ko16 = (lane >> 4) * 16;
  const int swz = (lane & 7) << 4;  // read-side swizzle (== (row&7)<<4)

  auto compute = [&](const char* Ab) {
    const char* Bb = Ab + BM * 128;
    bf16x8 af[2][MF], bfr[2][NF];
#pragma unroll
    for (int kk = 0; kk < 2; ++kk) {
      const int koff = (kk * 64 + ko16) ^ swz;
#pragma unroll
      for (int m = 0; m < MF; ++m)
        af[kk][m] = *(const bf16x8*)(Ab + (size_t)(wr * (BM / 2) + m * 16 + ar) * 128 + koff);
#pragma unroll
      for (int n = 0; n < NF; ++n)
        bfr[kk][n] = *(const bf16x8*)(Bb + (size_t)(wc * (BN / 2) + n * 16 + ar) * 128 + koff);
    }
#pragma unroll
    for (int kk = 0; kk < 2; ++kk)
#pragma unroll
      for (int m = 0; m < MF; ++m)
#pragma unroll
        for (int n = 0; n < NF; ++n)
          acc[m][n] = __builtin_amdgcn_mfma_f32_16x16x32_bf16(af[kk][m], bfr[kk][n], acc[m][n], 0, 0, 0);
  };

  // triangular-A K skip (ykv): rows i0..i0+BM-1 need k <= i0+BM-1
  int nt;
  if constexpr (MODE == 6) nt = nt6;
  else nt = TRI_A ? (i0 / 64 + BM / 64) : Ksize / 64;
  stage(0, 0);
  __syncthreads();
  int cur = 0;
  for (int t = 0; t < nt; ++t) {
    if (t + 1 < nt) {
      stage(cur ^ 1, t + 1);  // prefetch flies under compute
    } else {
      if constexpr (MODE == 3 || MODE == 4) stage_epi(cur ^ 1);
    }
    compute(lds + cur * BUFB);
    __syncthreads();  // drains prefetch (vmcnt 0) + guards buffer reuse
    cur ^= 1;
  }
  // after the final flip, `cur` indexes the buffer stage_epi wrote
  const char* lepi = lds + cur * BUFB;

#pragma unroll
  for (int m = 0; m < MF; ++m) {
    const int row0 = i0 + wr * (BM / 2) + m * 16 + ((lane >> 4) << 2);
#pragma unroll
    for (int n = 0; n < NF; ++n) {
      const int col = j0 + wc * (BN / 2) + n * 16 + (lane & 15);
      f32x4 c = acc[m][n];
      if constexpr (MODE == 4) {
        // qr = rope(relu(acc)); cos/sin from LDS-staged ctab slice
        const int rr0 = row0 - i0;
        const int ccol = col - j0;
        const uint4 q = *(const uint4*)(lepi + (size_t)(ccol >> 1) * 512 + rr0 * 4);
        const unsigned qw[4] = {q.x, q.y, q.z, q.w};
        const float sgn = (lane & 1) ? 1.f : -1.f;
#pragma unroll
        for (int r = 0; r < 4; ++r) {
          const float v = fmaxf(c[r], 0.f);
          const float pv = __shfl_xor(v, 1);
          const float cc = bf2f((unsigned short)(qw[r] & 0xffffu));
          const float ss = bf2f((unsigned short)(qw[r] >> 16));
          Ch[(size_t)(row0 + r) * ldc + col] = f2bf(v * cc + sgn * pv * ss);
        }
      } else if constexpr (MODE == 3) {
        // xy = relu(acc) * gate, gate = rope^{-1}(qr from LDS) clamped >= 0
        const int rr0 = row0 - i0;
        const int ccol = col - j0;
        const uint4 q4 = *(const uint4*)(ctab + (size_t)(col >> 1) * T_SEQ + row0);
        const unsigned qw[4] = {q4.x, q4.y, q4.z, q4.w};
        const float sgn2 = (lane & 1) ? -1.f : 1.f;
#pragma unroll
        for (int r = 0; r < 4; ++r) {
          const float qv =
              bf2f(*(const unsigned short*)(lepi + (size_t)(rr0 + r) * 256 + ccol * 2));
          const float pq = __shfl_xor(qv, 1);
          const float cc = bf2f((unsigned short)(qw[r] & 0xffffu));
          const float ss = bf2f((unsigned short)(qw[r] >> 16));
          const float gate = fmaxf(qv * cc + sgn2 * pq * ss, 0.f);
          Ch[(size_t)(row0 + r) * ldc + col] = f2bf(fmaxf(c[r], 0.f) * gate);
        }
      } else if constexpr (MODE == 6) {
        // tile-packed local write: Cf is the 128x128 tile base
#pragma unroll
        for (int r = 0; r < 4; ++r)
          Cf[(size_t)(row0 - i0 + r) * 128 + (col - j0)] = c[r];
      } else {
#pragma unroll
        for (int r = 0; r < 4; ++r) {
          const int row = row0 + r;
          const float v = c[r];
          if constexpr (MODE == 0 || MODE == 7) {
            Cf[(size_t)row * ldc + col] = v;
          } else if constexpr (MODE == 2) {
            Ch[(size_t)row * ldc + col] = (col < row) ? f2bf(v) : (unsigned short)0;
          }
        }
      }
    }
  }
}

extern "C" void kernel_launch(void* const* d_in, const int* in_sizes, int n_in,
                              void* d_out, int out_size, void* d_ws, size_t ws_size,
                              hipStream_t stream) {
  const int* idx = (const int*)d_in[0];
  const float* embed = (const float*)d_in[1];
  const float* enc = (const float*)d_in[2];
  const float* encv = (const float*)d_in[3];
  const float* dec = (const float*)d_in[4];
  const float* lmh = (const float*)d_in[5];
  float* out = (float*)d_out;

  char* p = (char*)d_ws;
  auto carve = [&](size_t bytes) -> void* {
    void* r = (void*)p;
    p += (bytes + 255) & ~(size_t)255;
    return r;
  };
  unsigned short* encT = (unsigned short*)carve((size_t)NH_C * N_DIM * D_DIM * 2);
  unsigned short* encvT = (unsigned short*)carve((size_t)NH_C * N_DIM * D_DIM * 2);
  unsigned short* decT = (unsigned short*)carve((size_t)D_DIM * NH_C * N_DIM * 2);
  unsigned short* lmT = (unsigned short*)carve((size_t)VOCAB_C * D_DIM * 2);
  float* x = (float*)carve((size_t)T_SEQ * D_DIM * 4);
  unsigned short* xb = (unsigned short*)carve((size_t)T_SEQ * D_DIM * 2);
  unsigned short* xT = (unsigned short*)carve((size_t)D_DIM * T_SEQ * 2);
  unsigned short* xy = (unsigned short*)carve((size_t)NH_C * T_SEQ * N_DIM * 2);  // mode3 out
  unsigned short* qr = (unsigned short*)carve((size_t)NH_C * T_SEQ * N_DIM * 2);
  unsigned short* sc = (unsigned short*)carve((size_t)NH_C * T_SEQ * T_SEQ * 2);
  float* ykv = (float*)carve((size_t)NH_C * T_SEQ * D_DIM * 4);
  unsigned short* ykvln = (unsigned short*)carve((size_t)NH_C * T_SEQ * D_DIM * 2);
  // ymlp region (32 x T x D f32 = 33.55 MB) doubles as the scores split-K=3
  // TILE-PACKED partial buffer (12 x 36 tiles x 64 KB = 28.3 MB <= 33.55 MB).
  // Lifetimes disjoint within a layer (scf32: scores->comb; ymlp: dec->update_x).
  float* ymlp = (float*)carve((size_t)KSPLIT_DEC * T_SEQ * D_DIM * 4);
  unsigned* cstab = (unsigned*)carve((size_t)(N_DIM / 2) * T_SEQ * 4);
  float* scf32 = ymlp;  // alias, no extra carve (28.3 MB < 33.55 MB)
  const bool split_ok = ((size_t)(p - (char*)d_ws) <= ws_size);

  const dim3 tb32(32, 8);
  k_transpose<<<dim3(N_DIM / 32, D_DIM / 32, NH_C), tb32, 0, stream>>>(
      enc, encT, D_DIM, N_DIM, (long)D_DIM * N_DIM, (long)N_DIM * D_DIM);
  k_transpose<<<dim3(N_DIM / 32, D_DIM / 32, NH_C), tb32, 0, stream>>>(
      encv, encvT, D_DIM, N_DIM, (long)D_DIM * N_DIM, (long)N_DIM * D_DIM);
  k_transpose<<<dim3(D_DIM / 32, (NH_C * N_DIM) / 32, 1), tb32, 0, stream>>>(
      dec, decT, NH_C * N_DIM, D_DIM, 0, 0);
  k_transpose<<<dim3(VOCAB_C / 32, D_DIM / 32, 1), tb32, 0, stream>>>(lmh, lmT, D_DIM, VOCAB_C, 0, 0);
  k_ropetab<<<((N_DIM / 2) * T_SEQ) / 256, 256, 0, stream>>>(cstab);
  k_embed_ln<<<T_SEQ, 64, 0, stream>>>(idx, embed, x, xb, xT);
  // one-time zeros for sc upper triangle (lower-tri-only writers below)
  (void)hipMemsetAsync(sc, 0, (size_t)NH_C * T_SEQ * T_SEQ * 2, stream);

  for (int l = 0; l < NLAYER; ++l) {
    // qr = rope(relu(x @ enc[h]))  -- xs is never materialized
    k_gemm<4, 128, 128, false, true><<<dim3(N_DIM / 128, T_SEQ / 128, NH_C), 256, 0, stream>>>(
        xb, D_DIM, 0, encT, D_DIM, (long)N_DIM * D_DIM, qr, N_DIM, (long)T_SEQ * N_DIM, nullptr, 0,
        nullptr, cstab, D_DIM);
    if (split_ok) {
      // scores: supertile tri grid x split-K=3 -> tile-packed f32 partials
      // (432 balanced blocks, K slices 42/43/43 x 64)
      k_gemm<6, 128, 128, false, false>
          <<<dim3(KSPLIT_SC * NH_C * (T_SEQ / 128) * (T_SEQ / 128 + 1) / 2, 1, 1), 256, 0, stream>>>(
              qr, N_DIM, (long)T_SEQ * N_DIM, qr, N_DIM, (long)T_SEQ * N_DIM, scf32, 128, 0,
              nullptr, 0, nullptr, nullptr, N_DIM);
      k_comb<KSPLIT_SC><<<(NH_C * T_SEQ * T_SEQ / 8) / 256, 256, 0, stream>>>(scf32, sc);
    } else {
      // fallback: 64^2 tri grid, direct masked bf16
      k_gemm<2, 64, 64, false, false>
          <<<dim3(NH_C * (T_SEQ / 64) * (T_SEQ / 64 + 1) / 2, 1, 1), 256, 0, stream>>>(
              qr, N_DIM, (long)T_SEQ * N_DIM, qr, N_DIM, (long)T_SEQ * N_DIM, sc, T_SEQ,
              (long)T_SEQ * T_SEQ, nullptr, 0, nullptr, nullptr, N_DIM);
    }
    // ykv = scores @ x  (triangular-A K skip)
    k_gemm<0, 64, 64, true, false><<<dim3(D_DIM / 64, T_SEQ / 64, NH_C), 256, 0, stream>>>(
        sc, T_SEQ, (long)T_SEQ * T_SEQ, xT, T_SEQ, 0, ykv, D_DIM, (long)T_SEQ * D_DIM, nullptr, 0,
        nullptr, nullptr, T_SEQ);
    k_ln_rows<<<NH_C * T_SEQ, 64, 0, stream>>>(ykv, ykvln);
    // xy = rope^{-1}(qr)-gate * relu(ykvln @ encv[h])  -> separate xy buffer
    k_gemm<3, 128, 128, false, true><<<dim3(N_DIM / 128, T_SEQ / 128, NH_C), 256, 0, stream>>>(
        ykvln, D_DIM, (long)T_SEQ * D_DIM, encvT, D_DIM, (long)N_DIM * D_DIM, xy, N_DIM,
        (long)T_SEQ * N_DIM, qr, (long)T_SEQ * N_DIM, nullptr, cstab, D_DIM);
    // ymlp partials = xy_flat @ decoder  (split-K=32, 128^2 tiles, f32 partials)
    // (overwrites the scf32 alias -- scf32 is dead after k_comb above)
    k_gemm<7, 128, 128, false, false>
        <<<dim3(D_DIM / 128, T_SEQ / 128, KSPLIT_DEC), 256, 0, stream>>>(
            xy, N_DIM, 0, decT, (long)(NH_C * N_DIM), 0, ymlp, D_DIM, (long)T_SEQ * D_DIM,
            nullptr, 0, nullptr, nullptr, (NH_C * N_DIM) / KSPLIT_DEC);
    // x = LN(x + LN(sum ymlp))
    k_update_x<KSPLIT_DEC><<<T_SEQ, 64, 0, stream>>>(ymlp, x, xb, xT);
  }
  // logits = x @ lm_head
  k_gemm<0, 64, 64, false, false><<<dim3(VOCAB_C / 64, T_SEQ / 64, 1), 256, 0, stream>>>(
      xb, D_DIM, 0, lmT, D_DIM, 0, out, VOCAB_C, 0, nullptr, 0, nullptr, nullptr, D_DIM);
}

// Round 19
// 605.893 us; speedup vs baseline: 1.0179x; 1.0179x over previous
//
#include <hip/hip_runtime.h>
#include <hip/hip_bf16.h>
#include <math.h>
#include <stdint.h>

#define T_SEQ 1024
#define D_DIM 256
#define NH_C 4
#define N_DIM 8192
#define VOCAB_C 256
#define NLAYER 3
#define TWO_PI_F 6.283185307179586f
#define KSPLIT_DEC 32
#define KSPLIT_SC 3

typedef __bf16 bf16x8 __attribute__((ext_vector_type(8)));
typedef float f32x4 __attribute__((ext_vector_type(4)));

__device__ __forceinline__ unsigned short f2bf(float f) {
  unsigned u = __builtin_bit_cast(unsigned, f);
  u += 0x7fffu + ((u >> 16) & 1u);
  return (unsigned short)(u >> 16);
}
__device__ __forceinline__ float bf2f(unsigned short h) {
  unsigned u = ((unsigned)h) << 16;
  return __builtin_bit_cast(float, u);
}
__device__ __forceinline__ unsigned pack2(float a, float b) {
  return (unsigned)f2bf(a) | ((unsigned)f2bf(b) << 16);
}

// direct global->LDS 16B async copy. LDS dest = wave-uniform base + lane*16
// (linear); bank swizzle on the GLOBAL source col, mirrored on ds_read (rule #21).
typedef __attribute__((address_space(3))) uint32_t lds_u32;
typedef __attribute__((address_space(1))) const uint32_t glob_u32;
__device__ __forceinline__ void gload_lds16(const void* g, void* l) {
  __builtin_amdgcn_global_load_lds(reinterpret_cast<glob_u32*>(reinterpret_cast<uintptr_t>(g)),
                                   reinterpret_cast<lds_u32*>(reinterpret_cast<uintptr_t>(l)), 16, 0,
                                   0);
}

// ---------------- transpose f32 [R][C] -> bf16 [C][R], batched over z ----------
__global__ void k_transpose(const float* __restrict__ src, unsigned short* __restrict__ dst,
                            int R, int C, long sB, long dB) {
  __shared__ float tile[32][33];
  const int b = blockIdx.z;
  src += (size_t)b * sB;
  dst += (size_t)b * dB;
  const int c0 = blockIdx.x * 32, r0 = blockIdx.y * 32;
  const int tx = threadIdx.x, ty = threadIdx.y;  // 32 x 8
#pragma unroll
  for (int i = 0; i < 32; i += 8)
    tile[ty + i][tx] = src[(size_t)(r0 + ty + i) * C + (c0 + tx)];
  __syncthreads();
#pragma unroll
  for (int i = 0; i < 32; i += 8)
    dst[(size_t)(c0 + ty + i) * R + (r0 + tx)] = f2bf(tile[tx][ty + i]);
}

// ------- rope cos/sin table, TRANSPOSED + bf16-packed: cs[pair][t] = c|s<<16 ----
__global__ void k_ropetab(unsigned* __restrict__ cs) {
  const int id = blockIdx.x * 256 + threadIdx.x;  // pair*1024 + t
  const int pair = id >> 10, t = id & 1023;
  const float freq = exp2f(-(float)pair * (1.0f / 256.0f)) * (1.0f / TWO_PI_F);
  float ph = (float)t * freq;
  ph -= floorf(ph);
  float s, c;
  __sincosf(ph * TWO_PI_F, &s, &c);
  cs[id] = pack2(c, s);
}

// ---------------- one-wave LayerNorm stats over 256 elems ----------------------
__device__ __forceinline__ void stats256(float4 v, float& mu, float& rs) {
  float s = v.x + v.y + v.z + v.w;
  float ss = v.x * v.x + v.y * v.y + v.z * v.z + v.w * v.w;
#pragma unroll
  for (int o = 1; o < 64; o <<= 1) { s += __shfl_xor(s, o); ss += __shfl_xor(ss, o); }
  mu = s * (1.0f / 256.0f);
  float var = ss * (1.0f / 256.0f) - mu * mu;
  rs = rsqrtf(var + 1e-5f);
}

__global__ void k_embed_ln(const int* __restrict__ idx, const float* __restrict__ embed,
                           float* __restrict__ x, unsigned short* __restrict__ xb,
                           unsigned short* __restrict__ xT) {
  const int t = blockIdx.x, lane = threadIdx.x;  // 64 threads
  const float* row = embed + (size_t)idx[t] * D_DIM;
  float4 v = ((const float4*)row)[lane];
  float mu, rs;
  stats256(v, mu, rs);
  float4 o = make_float4((v.x - mu) * rs, (v.y - mu) * rs, (v.z - mu) * rs, (v.w - mu) * rs);
  ((float4*)(x + (size_t)t * D_DIM))[lane] = o;
  ((uint2*)(xb + (size_t)t * D_DIM))[lane] = make_uint2(pack2(o.x, o.y), pack2(o.z, o.w));
  const int d0 = lane * 4;
  xT[(size_t)(d0 + 0) * T_SEQ + t] = f2bf(o.x);
  xT[(size_t)(d0 + 1) * T_SEQ + t] = f2bf(o.y);
  xT[(size_t)(d0 + 2) * T_SEQ + t] = f2bf(o.z);
  xT[(size_t)(d0 + 3) * T_SEQ + t] = f2bf(o.w);
}

__global__ void k_ln_rows(const float* __restrict__ in, unsigned short* __restrict__ outb) {
  const int r = blockIdx.x, lane = threadIdx.x;
  float4 v = ((const float4*)(in + (size_t)r * D_DIM))[lane];
  float mu, rs;
  stats256(v, mu, rs);
  ((uint2*)(outb + (size_t)r * D_DIM))[lane] =
      make_uint2(pack2((v.x - mu) * rs, (v.y - mu) * rs), pack2((v.z - mu) * rs, (v.w - mu) * rs));
}

// x = LN(x + LN(sum_p ymlp[p]))
template <int NP>
__global__ void k_update_x(const float* __restrict__ ymlp, float* __restrict__ x,
                           unsigned short* __restrict__ xb, unsigned short* __restrict__ xT) {
  const int t = blockIdx.x, lane = threadIdx.x;
  float4 m = make_float4(0.f, 0.f, 0.f, 0.f);
#pragma unroll
  for (int pp = 0; pp < NP; ++pp) {
    float4 q = ((const float4*)(ymlp + (size_t)pp * T_SEQ * D_DIM + (size_t)t * D_DIM))[lane];
    m.x += q.x; m.y += q.y; m.z += q.z; m.w += q.w;
  }
  float mu1, rs1;
  stats256(m, mu1, rs1);
  float4 xv = ((const float4*)(x + (size_t)t * D_DIM))[lane];
  float4 z = make_float4(xv.x + (m.x - mu1) * rs1, xv.y + (m.y - mu1) * rs1,
                         xv.z + (m.z - mu1) * rs1, xv.w + (m.w - mu1) * rs1);
  float mu2, rs2;
  stats256(z, mu2, rs2);
  float4 o = make_float4((z.x - mu2) * rs2, (z.y - mu2) * rs2, (z.z - mu2) * rs2, (z.w - mu2) * rs2);
  ((float4*)(x + (size_t)t * D_DIM))[lane] = o;
  ((uint2*)(xb + (size_t)t * D_DIM))[lane] = make_uint2(pack2(o.x, o.y), pack2(o.z, o.w));
  const int d0 = lane * 4;
  xT[(size_t)(d0 + 0) * T_SEQ + t] = f2bf(o.x);
  xT[(size_t)(d0 + 1) * T_SEQ + t] = f2bf(o.y);
  xT[(size_t)(d0 + 2) * T_SEQ + t] = f2bf(o.z);
  xT[(size_t)(d0 + 3) * T_SEQ + t] = f2bf(o.w);
}

// combine NP TILE-PACKED split-K score partials + strict-lower mask -> bf16.
// Partials layout: [(h*NP+pp)][tile36][128][128] f32, tile = by*(by+1)/2+bx over
// 128x128 lower-tri tiles. Upper-tri of sc keeps its one-time memset zeros.
template <int NP>
__global__ void k_comb(const float* __restrict__ sp, unsigned short* __restrict__ sc) {
  const size_t gid = (size_t)blockIdx.x * 256 + threadIdx.x;  // per 8 elems
  const size_t e0 = gid * 8;
  const int s = (int)(e0 & (T_SEQ - 1));
  const int t = (int)((e0 >> 10) & (T_SEQ - 1));
  if (s >= t) return;  // entire 8-run masked (strict lower: need s < t)
  const int h = (int)(e0 >> 20);
  const int by = t >> 7, bx = s >> 7;                       // 128-tile coords
  const size_t tin = (size_t)(by * (by + 1) / 2 + bx);      // lower-tri tile idx
  const size_t off = (size_t)(t & 127) * 128 + (s & 127);   // in-tile offset
  float v[8] = {0.f, 0.f, 0.f, 0.f, 0.f, 0.f, 0.f, 0.f};
#pragma unroll
  for (int pp = 0; pp < NP; ++pp) {
    const float* a = sp + (((size_t)(h * NP + pp) * 36 + tin) << 14) + off;
    float4 a0 = *(const float4*)a, a1 = *(const float4*)(a + 4);
    v[0] += a0.x; v[1] += a0.y; v[2] += a0.z; v[3] += a0.w;
    v[4] += a1.x; v[5] += a1.y; v[6] += a1.z; v[7] += a1.w;
  }
  unsigned short o[8];
#pragma unroll
  for (int j = 0; j < 8; ++j) o[j] = (s + j < t) ? f2bf(v[j]) : (unsigned short)0;
  *(uint4*)(sc + e0) = *(uint4*)o;
}

// ---------------- pipelined NT bf16 MFMA GEMM: C[i][j] = sum_k A[i][k]*B[j][k] --
// 2-phase double-buffer, global_load_lds staging, both-sides XOR bank swizzle,
// bijective XCD-chunked block swizzle.
// MODE 0: f32 store | 2: scores exact lower-tri grid, strict-lower mask -> bf16
// MODE 3: xy = relu(acc) * inverse-rope-gate(extra=qr) -> bf16 to SEPARATE xy
//         buffer (no aliasing)
// MODE 4: qr = rope(relu(acc)) -> bf16 ONLY (xs never materialized)
// MODE 6: scores supertile tri grid + split-K=3 (uneven 42/43/43 nt),
//         TILE-PACKED f32 partials (local 128x128 write at tile base)
// MODE 7: split-K f32 partials (decoder; A = xy [h][T][N] head-flat K)
template <int MODE, int BM, int BN, bool TRI_A, bool SWAPXY>
__global__ __launch_bounds__(256) void k_gemm(const unsigned short* __restrict__ A, long lda, long sAz,
                                              const unsigned short* __restrict__ B, long ldb, long sBz,
                                              void* __restrict__ Cv, long ldc, long sCz,
                                              const unsigned short* __restrict__ extra, long sEz,
                                              unsigned short* __restrict__ C2,
                                              const unsigned* __restrict__ ctab, int Ksize) {
  constexpr int MF = BM / 32;
  constexpr int NF = BN / 32;
  constexpr int BUFB = (BM + BN) * 128;  // bytes per LDS buffer (BK=64)

  // T1: bijective XCD-chunked swizzle (m204) over the full linear grid
  const unsigned nbx = gridDim.x, nby = gridDim.y;
  const unsigned total = nbx * nby * gridDim.z;
  const unsigned lid = (blockIdx.z * nby + blockIdx.y) * nbx + blockIdx.x;
  const unsigned qq = total >> 3, rr = total & 7;
  const unsigned xcd = lid & 7, loc = lid >> 3;
  const unsigned wg = (xcd < rr ? xcd * (qq + 1) : rr * (qq + 1) + (xcd - rr) * qq) + loc;

  int bx, by, bz, zAB, kbase = 0, nt6 = 0, tIdx = 0;
  if constexpr (MODE == 2 || MODE == 6) {
    constexpr int NRT = T_SEQ / BM;
    constexpr int TPH = NRT * (NRT + 1) / 2;
    const int zz = wg / TPH;
    const int tt = wg % TPH;
    if constexpr (MODE == 6 && NRT == 8) {
      // 2x2 supertile traversal of the 8x8 lower triangle
      int srow, rem;
      if (tt < 3)       { srow = 0; rem = tt; }
      else if (tt < 10) { srow = 1; rem = tt - 3; }
      else if (tt < 21) { srow = 2; rem = tt - 10; }
      else              { srow = 3; rem = tt - 21; }
      int scol, lr, lc;
      if (rem < 4 * srow) {
        scol = rem >> 2;
        lr = rem & 1;
        lc = (rem >> 1) & 1;
      } else {
        const int l = rem - 4 * srow;
        scol = srow;
        lr = (l >= 1);
        lc = (l == 2);
      }
      by = srow * 2 + lr;
      bx = scol * 2 + lc;
    } else {
      by = (int)((sqrtf(8.0f * (float)tt + 1.0f) - 1.0f) * 0.5f);
      if (by > NRT - 1) by = NRT - 1;
      while ((by + 1) * (by + 2) / 2 <= tt) ++by;
      while (by * (by + 1) / 2 > tt) --by;
      bx = tt - by * (by + 1) / 2;  // bx <= by
    }
    bz = zz;
    if constexpr (MODE == 6) {
      // split-K=3, uneven 64-unit slices: s0 = (slice*ub)/3 -> 42/43/43
      const int ub = Ksize / 64;
      const int slice = zz % KSPLIT_SC;
      zAB = zz / KSPLIT_SC;  // head
      const int s0 = (slice * ub) / KSPLIT_SC;
      const int s1 = ((slice + 1) * ub) / KSPLIT_SC;
      kbase = s0 * 64;
      nt6 = s1 - s0;
      tIdx = by * (by + 1) / 2 + bx;  // packed lower-tri tile index
    } else {
      zAB = zz;
    }
  } else if constexpr (SWAPXY) {
    by = wg % nby;
    bx = (wg / nby) % nbx;
    bz = wg / (nbx * nby);
    zAB = bz;
  } else {
    bx = wg % nbx;
    by = (wg / nbx) % nby;
    bz = wg / (nbx * nby);
    zAB = bz;
  }
  if constexpr (MODE == 7) kbase = bz * Ksize;

  const int i0 = by * BM;
  const int j0 = bx * BN;

  A += (size_t)zAB * sAz;
  B += (size_t)zAB * sBz;
  float* Cf;
  if constexpr (MODE == 6) {
    Cf = (float*)Cv + (((size_t)bz * 36 + tIdx) << 14);  // tile base (128x128 f32)
  } else {
    Cf = (float*)Cv + (size_t)bz * sCz;
  }
  unsigned short* Ch = (unsigned short*)Cv + (size_t)bz * sCz;
  const unsigned short* E = extra ? extra + (size_t)bz * sEz : nullptr;

  const int tid = threadIdx.x;
  const int lane = tid & 63, w = tid >> 6;
  const int wr = w >> 1, wc = w & 1;  // 2x2 wave grid

  __shared__ __align__(16) char lds[2 * BUFB];

  f32x4 acc[MF][NF];
#pragma unroll
  for (int m = 0; m < MF; ++m)
#pragma unroll
    for (int n = 0; n < NF; ++n) acc[m][n] = f32x4{0.f, 0.f, 0.f, 0.f};

  const char* Abytes = (const char*)A;
  const char* Bbytes = (const char*)B;
  const size_t ldab = (size_t)((MODE == 7) ? N_DIM : lda) * 2;
  const size_t ldbb = (size_t)ldb * 2;
  const int lr2 = lane >> 3;                        // 8 rows x 128B per wave-issue
  const int scol2 = ((lane & 7) * 16) ^ (lr2 << 4); // pre-swizzled source col

  auto stage = [&](int buf, int kt) {
    const int kk = kbase + kt * 64;
    const char* Ag;
    if constexpr (MODE == 7) {  // A = xy [h][T][N], flat k = h*N + n
      Ag = Abytes +
           ((size_t)(kk >> 13) * ((size_t)T_SEQ * N_DIM) + (size_t)i0 * N_DIM + (kk & (N_DIM - 1))) * 2;
    } else {
      Ag = Abytes + ((size_t)i0 * lda + kk) * 2;
    }
    const char* Bg = Bbytes + ((size_t)j0 * ldb + kk) * 2;
    char* lb = lds + buf * BUFB;
#pragma unroll
    for (int it = 0; it < BM / 32; ++it) {
      const int r0 = (w + 4 * it) * 8;
      gload_lds16(Ag + (size_t)(r0 + lr2) * ldab + scol2, lb + r0 * 128);
    }
#pragma unroll
    for (int it = 0; it < BN / 32; ++it) {
      const int r0 = (w + 4 * it) * 8;
      gload_lds16(Bg + (size_t)(r0 + lr2) * ldbb + scol2, lb + BM * 128 + r0 * 128);
    }
  };

  const int ar = lane & 15;
  const int ko16 = (lane >> 4) * 16;
  const int swz = (lane & 7) << 4;  // read-side swizzle (== (row&7)<<4)

  auto compute = [&](const char* Ab) {
    const char* Bb = Ab + BM * 128;
    bf16x8 af[2][MF], bfr[2][NF];
#pragma unroll
    for (int kk = 0; kk < 2; ++kk) {
      const int koff = (kk * 64 + ko16) ^ swz;
#pragma unroll
      for (int m = 0; m < MF; ++m)
        af[kk][m] = *(const bf16x8*)(Ab + (size_t)(wr * (BM / 2) + m * 16 + ar) * 128 + koff);
#pragma unroll
      for (int n = 0; n < NF; ++n)
        bfr[kk][n] = *(const bf16x8*)(Bb + (size_t)(wc * (BN / 2) + n * 16 + ar) * 128 + koff);
    }
#pragma unroll
    for (int kk = 0; kk < 2; ++kk)
#pragma unroll
      for (int m = 0; m < MF; ++m)
#pragma unroll
        for (int n = 0; n < NF; ++n)
          acc[m][n] = __builtin_amdgcn_mfma_f32_16x16x32_bf16(af[kk][m], bfr[kk][n], acc[m][n], 0, 0, 0);
  };

  // triangular-A K skip (ykv): rows i0..i0+BM-1 need k <= i0+BM-1
  int nt;
  if constexpr (MODE == 6) nt = nt6;
  else nt = TRI_A ? (i0 / 64 + BM / 64) : Ksize / 64;
  stage(0, 0);
  __syncthreads();
  int cur = 0;
  for (int t = 0; t < nt; ++t) {
    if (t + 1 < nt) stage(cur ^ 1, t + 1);  // prefetch flies under compute
    compute(lds + cur * BUFB);
    __syncthreads();
    cur ^= 1;
  }

#pragma unroll
  for (int m = 0; m < MF; ++m) {
    const int row0 = i0 + wr * (BM / 2) + m * 16 + ((lane >> 4) << 2);
#pragma unroll
    for (int n = 0; n < NF; ++n) {
      const int col = j0 + wc * (BN / 2) + n * 16 + (lane & 15);
      f32x4 c = acc[m][n];
      if constexpr (MODE == 4) {
        // qr = rope(relu(acc)) ONLY. Pair partner via shfl_xor(1); cos/sin
        // packed bf16 from transposed table [pair][t]. (scalar stores, proven)
        const uint4 q = *(const uint4*)(ctab + (size_t)(col >> 1) * T_SEQ + row0);
        const unsigned qw[4] = {q.x, q.y, q.z, q.w};
        const float sgn = (lane & 1) ? 1.f : -1.f;
#pragma unroll
        for (int r = 0; r < 4; ++r) {
          const float v = fmaxf(c[r], 0.f);
          const float pv = __shfl_xor(v, 1);
          const float cc = bf2f((unsigned short)(qw[r] & 0xffffu));
          const float ss = bf2f((unsigned short)(qw[r] >> 16));
          Ch[(size_t)(row0 + r) * ldc + col] = f2bf(v * cc + sgn * pv * ss);
        }
      } else if constexpr (MODE == 3) {
        // xy = relu(acc) * gate, gate = rope^{-1}(qr) clamped >=0.
        // Inverse rotation: x0 = q0*c + q1*s ; x1 = q1*c - q0*s.
        const uint4 q4 = *(const uint4*)(ctab + (size_t)(col >> 1) * T_SEQ + row0);
        const unsigned qw[4] = {q4.x, q4.y, q4.z, q4.w};
        const float sgn2 = (lane & 1) ? -1.f : 1.f;
#pragma unroll
        for (int r = 0; r < 4; ++r) {
          const float qv = bf2f(E[(size_t)(row0 + r) * ldc + col]);
          const float pq = __shfl_xor(qv, 1);
          const float cc = bf2f((unsigned short)(qw[r] & 0xffffu));
          const float ss = bf2f((unsigned short)(qw[r] >> 16));
          const float gate = fmaxf(qv * cc + sgn2 * pq * ss, 0.f);
          Ch[(size_t)(row0 + r) * ldc + col] = f2bf(fmaxf(c[r], 0.f) * gate);
        }
      } else if constexpr (MODE == 6) {
        // tile-packed local write: Cf is the 128x128 tile base
#pragma unroll
        for (int r = 0; r < 4; ++r)
          Cf[(size_t)(row0 - i0 + r) * 128 + (col - j0)] = c[r];
      } else {
#pragma unroll
        for (int r = 0; r < 4; ++r) {
          const int row = row0 + r;
          const float v = c[r];
          if constexpr (MODE == 0 || MODE == 7) {
            Cf[(size_t)row * ldc + col] = v;
          } else if constexpr (MODE == 2) {
            Ch[(size_t)row * ldc + col] = (col < row) ? f2bf(v) : (unsigned short)0;
          }
        }
      }
    }
  }
}

extern "C" void kernel_launch(void* const* d_in, const int* in_sizes, int n_in,
                              void* d_out, int out_size, void* d_ws, size_t ws_size,
                              hipStream_t stream) {
  const int* idx = (const int*)d_in[0];
  const float* embed = (const float*)d_in[1];
  const float* enc = (const float*)d_in[2];
  const float* encv = (const float*)d_in[3];
  const float* dec = (const float*)d_in[4];
  const float* lmh = (const float*)d_in[5];
  float* out = (float*)d_out;

  char* p = (char*)d_ws;
  auto carve = [&](size_t bytes) -> void* {
    void* r = (void*)p;
    p += (bytes + 255) & ~(size_t)255;
    return r;
  };
  unsigned short* encT = (unsigned short*)carve((size_t)NH_C * N_DIM * D_DIM * 2);
  unsigned short* encvT = (unsigned short*)carve((size_t)NH_C * N_DIM * D_DIM * 2);
  unsigned short* decT = (unsigned short*)carve((size_t)D_DIM * NH_C * N_DIM * 2);
  unsigned short* lmT = (unsigned short*)carve((size_t)VOCAB_C * D_DIM * 2);
  float* x = (float*)carve((size_t)T_SEQ * D_DIM * 4);
  unsigned short* xb = (unsigned short*)carve((size_t)T_SEQ * D_DIM * 2);
  unsigned short* xT = (unsigned short*)carve((size_t)D_DIM * T_SEQ * 2);
  unsigned short* xy = (unsigned short*)carve((size_t)NH_C * T_SEQ * N_DIM * 2);  // mode3 out
  unsigned short* qr = (unsigned short*)carve((size_t)NH_C * T_SEQ * N_DIM * 2);
  unsigned short* sc = (unsigned short*)carve((size_t)NH_C * T_SEQ * T_SEQ * 2);
  float* ykv = (float*)carve((size_t)NH_C * T_SEQ * D_DIM * 4);
  unsigned short* ykvln = (unsigned short*)carve((size_t)NH_C * T_SEQ * D_DIM * 2);
  // ymlp region (32 x T x D f32 = 33.55 MB) doubles as the scores split-K=3
  // TILE-PACKED partial buffer (12 x 36 tiles x 64 KB = 28.3 MB <= 33.55 MB).
  // Lifetimes disjoint within a layer (scf32: scores->comb; ymlp: dec->update_x).
  float* ymlp = (float*)carve((size_t)KSPLIT_DEC * T_SEQ * D_DIM * 4);
  unsigned* cstab = (unsigned*)carve((size_t)(N_DIM / 2) * T_SEQ * 4);
  float* scf32 = ymlp;  // alias, no extra carve (28.3 MB < 33.55 MB)
  const bool split_ok = ((size_t)(p - (char*)d_ws) <= ws_size);

  const dim3 tb32(32, 8);
  k_transpose<<<dim3(N_DIM / 32, D_DIM / 32, NH_C), tb32, 0, stream>>>(
      enc, encT, D_DIM, N_DIM, (long)D_DIM * N_DIM, (long)N_DIM * D_DIM);
  k_transpose<<<dim3(N_DIM / 32, D_DIM / 32, NH_C), tb32, 0, stream>>>(
      encv, encvT, D_DIM, N_DIM, (long)D_DIM * N_DIM, (long)N_DIM * D_DIM);
  k_transpose<<<dim3(D_DIM / 32, (NH_C * N_DIM) / 32, 1), tb32, 0, stream>>>(
      dec, decT, NH_C * N_DIM, D_DIM, 0, 0);
  k_transpose<<<dim3(VOCAB_C / 32, D_DIM / 32, 1), tb32, 0, stream>>>(lmh, lmT, D_DIM, VOCAB_C, 0, 0);
  k_ropetab<<<((N_DIM / 2) * T_SEQ) / 256, 256, 0, stream>>>(cstab);
  k_embed_ln<<<T_SEQ, 64, 0, stream>>>(idx, embed, x, xb, xT);
  // one-time zeros for sc upper triangle (lower-tri-only writers below)
  (void)hipMemsetAsync(sc, 0, (size_t)NH_C * T_SEQ * T_SEQ * 2, stream);

  for (int l = 0; l < NLAYER; ++l) {
    // qr = rope(relu(x @ enc[h]))  -- xs is never materialized
    k_gemm<4, 128, 128, false, true><<<dim3(N_DIM / 128, T_SEQ / 128, NH_C), 256, 0, stream>>>(
        xb, D_DIM, 0, encT, D_DIM, (long)N_DIM * D_DIM, qr, N_DIM, (long)T_SEQ * N_DIM, nullptr, 0,
        nullptr, cstab, D_DIM);
    if (split_ok) {
      // scores: supertile tri grid x split-K=3 -> tile-packed f32 partials
      // (432 balanced blocks, K slices 42/43/43 x 64)
      k_gemm<6, 128, 128, false, false>
          <<<dim3(KSPLIT_SC * NH_C * (T_SEQ / 128) * (T_SEQ / 128 + 1) / 2, 1, 1), 256, 0, stream>>>(
              qr, N_DIM, (long)T_SEQ * N_DIM, qr, N_DIM, (long)T_SEQ * N_DIM, scf32, 128, 0,
              nullptr, 0, nullptr, nullptr, N_DIM);
      k_comb<KSPLIT_SC><<<(NH_C * T_SEQ * T_SEQ / 8) / 256, 256, 0, stream>>>(scf32, sc);
    } else {
      // fallback: 64^2 tri grid, direct masked bf16
      k_gemm<2, 64, 64, false, false>
          <<<dim3(NH_C * (T_SEQ / 64) * (T_SEQ / 64 + 1) / 2, 1, 1), 256, 0, stream>>>(
              qr, N_DIM, (long)T_SEQ * N_DIM, qr, N_DIM, (long)T_SEQ * N_DIM, sc, T_SEQ,
              (long)T_SEQ * T_SEQ, nullptr, 0, nullptr, nullptr, N_DIM);
    }
    // ykv = scores @ x  (triangular-A K skip)
    k_gemm<0, 64, 64, true, false><<<dim3(D_DIM / 64, T_SEQ / 64, NH_C), 256, 0, stream>>>(
        sc, T_SEQ, (long)T_SEQ * T_SEQ, xT, T_SEQ, 0, ykv, D_DIM, (long)T_SEQ * D_DIM, nullptr, 0,
        nullptr, nullptr, T_SEQ);
    k_ln_rows<<<NH_C * T_SEQ, 64, 0, stream>>>(ykv, ykvln);
    // xy = rope^{-1}(qr)-gate * relu(ykvln @ encv[h])  -> separate xy buffer
    k_gemm<3, 128, 128, false, true><<<dim3(N_DIM / 128, T_SEQ / 128, NH_C), 256, 0, stream>>>(
        ykvln, D_DIM, (long)T_SEQ * D_DIM, encvT, D_DIM, (long)N_DIM * D_DIM, xy, N_DIM,
        (long)T_SEQ * N_DIM, qr, (long)T_SEQ * N_DIM, nullptr, cstab, D_DIM);
    // ymlp partials = xy_flat @ decoder  (split-K=32, 128^2 tiles, f32 partials)
    // (overwrites the scf32 alias -- scf32 is dead after k_comb above)
    k_gemm<7, 128, 128, false, false>
        <<<dim3(D_DIM / 128, T_SEQ / 128, KSPLIT_DEC), 256, 0, stream>>>(
            xy, N_DIM, 0, decT, (long)(NH_C * N_DIM), 0, ymlp, D_DIM, (long)T_SEQ * D_DIM,
            nullptr, 0, nullptr, nullptr, (NH_C * N_DIM) / KSPLIT_DEC);
    // x = LN(x + LN(sum ymlp))
    k_update_x<KSPLIT_DEC><<<T_SEQ, 64, 0, stream>>>(ymlp, x, xb, xT);
  }
  // logits = x @ lm_head
  k_gemm<0, 64, 64, false, false><<<dim3(VOCAB_C / 64, T_SEQ / 64, 1), 256, 0, stream>>>(
      xb, D_DIM, 0, lmT, D_DIM, 0, out, VOCAB_C, 0, nullptr, 0, nullptr, nullptr, D_DIM);
}